// Round 11
// baseline (195.879 us; speedup 1.0000x reference)
//
#include <hip/hip_runtime.h>

#define DI __device__ __forceinline__

typedef unsigned short u16;
typedef __attribute__((ext_vector_type(8))) short s16x8;
typedef __attribute__((ext_vector_type(8))) unsigned short u16x8;
typedef __attribute__((ext_vector_type(4))) float f32x4;
typedef __attribute__((ext_vector_type(16))) float f32x16;

DI u16 f2bf(float x) {
  union { float f; unsigned u; } a; a.f = x;
  unsigned r = a.u + 0x7FFFu + ((a.u >> 16) & 1u);
  return (u16)(r >> 16);
}
DI float bf2f(u16 u) {
  union { unsigned u; float f; } a; a.u = ((unsigned)u) << 16;
  return a.f;
}
DI void gload16(const void* g, void* l) {
  __builtin_amdgcn_global_load_lds(
      (const __attribute__((address_space(1))) unsigned int*)g,
      (__attribute__((address_space(3))) unsigned int*)l, 16, 0, 0);
}
DI f32x4 mfma16(s16x8 a, s16x8 b, f32x4 c) {
  return __builtin_amdgcn_mfma_f32_16x16x32_bf16(a, b, c, 0, 0, 0);
}
DI f32x16 mfma32(s16x8 a, s16x8 b, f32x16 c) {
  return __builtin_amdgcn_mfma_f32_32x32x16_bf16(a, b, c, 0, 0, 0);
}
DI float exp2fast(float x) {  // raw v_exp_f32: 2^x, underflows to 0
  float r;
  asm("v_exp_f32 %0, %1" : "=v"(r) : "v"(x));
  return r;
}

DI void store4(u16* p, f32x4 v) {
  union { u16 u[4]; unsigned long long ll; } o;
  o.u[0] = f2bf(v[0]); o.u[1] = f2bf(v[1]); o.u[2] = f2bf(v[2]); o.u[3] = f2bf(v[3]);
  *(unsigned long long*)p = o.ll;  // 8B
}
DI void store4(float* p, f32x4 v) { *(f32x4*)p = v; }  // 16B

#define SBAR() asm volatile("s_barrier" ::: "memory")

// ================= fused prep: cvt(hidden) + W_pack^T + W_o^T + rope table =================
__global__ __launch_bounds__(256) void prep_kernel(
    const float* __restrict__ hidden, const float* __restrict__ W_pack,
    const float* __restrict__ W_o, u16* __restrict__ hA, u16* __restrict__ wpT,
    u16* __restrict__ woT, float* __restrict__ cosT, float* __restrict__ sinT) {
  int bi = blockIdx.x;
  int t = threadIdx.x;
  if (bi < 4096) {
    int i = bi * 256 + t;
    const float4* p = (const float4*)hidden + (size_t)i * 2;
    float4 a = p[0], b = p[1];
    u16x8 o;
    o[0] = f2bf(a.x); o[1] = f2bf(a.y); o[2] = f2bf(a.z); o[3] = f2bf(a.w);
    o[4] = f2bf(b.x); o[5] = f2bf(b.y); o[6] = f2bf(b.z); o[7] = f2bf(b.w);
    *((u16x8*)hA + i) = o;
  } else if (bi < 7168) {
    const float* W; u16* Wt; int R, C, c0, r0;
    if (bi < 6144) {
      int idx = bi - 4096;
      W = W_pack; Wt = wpT; R = 2048; C = 4096;
      c0 = (idx & 63) * 64; r0 = (idx >> 6) * 64;
    } else {
      int idx = bi - 6144;
      W = W_o; Wt = woT; R = 2048; C = 2048;
      c0 = (idx & 31) * 64; r0 = (idx >> 5) * 64;
    }
    __shared__ u16 tile[64][65];
#pragma unroll
    for (int i = 0; i < 16; ++i) {
      int flat = i * 256 + t;
      int r = flat >> 6, c = flat & 63;
      tile[r][c] = f2bf(W[(size_t)(r0 + r) * C + (c0 + c)]);
    }
    __syncthreads();
#pragma unroll
    for (int i = 0; i < 16; ++i) {
      int flat = i * 256 + t;
      int c = flat >> 6, r = flat & 63;
      Wt[(size_t)(c0 + c) * R + (r0 + r)] = tile[r][c];
    }
  } else {
    int i = (bi - 7168) * 256 + t;
    int s = i >> 6, d = i & 63;
    float inv = expf(-(float)d * (11.5129254649702295f / 64.f));
    float f = (float)s * inv;
    cosT[i] = cosf(f);
    sinT[i] = sinf(f);
  }
}

// ================= 256x256 ring-buffer bf16 GEMM (gemm1) =================
__global__ __launch_bounds__(512, 2) void gemm_ring_kernel(
    const u16* __restrict__ A, const u16* __restrict__ Bt, u16* __restrict__ C,
    int M, int N, int K) {
  constexpr int BSZ = 32768;  // A 16KB + B 16KB
  __shared__ __align__(16) char lds[4 * BSZ];
  int nwg = gridDim.x, bid = blockIdx.x;
  int cpx = nwg >> 3;
  int swz = (bid & 7) * cpx + (bid >> 3);  // bijective: nwg % 8 == 0
  int ntn = N >> 8;
  int bm = swz / ntn, bn = swz - bm * ntn;
  int m0 = bm << 8, n0 = bn << 8;
  int t = threadIdx.x, w = t >> 6, l = t & 63;
  int wm = w >> 2, wn = w & 3;
  int NT = K >> 5;  // K-tiles of 32

  unsigned srcA[2], srcB[2];
  unsigned scol = (unsigned)(((t & 3) ^ ((t >> 3) & 3)) << 4);
#pragma unroll
  for (int u = 0; u < 2; ++u) {
    srcA[u] = (unsigned)(m0 + u * 128 + (t >> 2)) * (unsigned)(K * 2) + scol;
    srcB[u] = (unsigned)(n0 + u * 128 + (t >> 2)) * (unsigned)(K * 2) + scol;
  }
  unsigned dstT = (unsigned)(t * 16);
  const char* Ab = (const char*)A;
  const char* Bb = (const char*)Bt;

#define STAGE(tile) do { int _t = (tile); if (_t < NT) {                        \
    char* _bb = lds + (size_t)(_t & 3) * BSZ;                                    \
    unsigned _k = (unsigned)_t * 64u;                                            \
    gload16(Ab + (size_t)(srcA[0] + _k), _bb + dstT);                            \
    gload16(Ab + (size_t)(srcA[1] + _k), _bb + 8192 + dstT);                     \
    gload16(Bb + (size_t)(srcB[0] + _k), _bb + 16384 + dstT);                    \
    gload16(Bb + (size_t)(srcB[1] + _k), _bb + 24576 + dstT);                    \
  } } while (0)

  int lanemix = ((l & 15) << 6) + ((((l >> 4) ^ ((l >> 1) & 3))) << 4);

  f32x4 acc[8][4] = {};
  s16x8 af[8], bfr[4];

  STAGE(0); STAGE(1); STAGE(2);
  asm volatile("s_waitcnt vmcnt(8)" ::: "memory");
  SBAR();

  for (int tt = 0; tt < NT; ++tt) {
    char* buf = lds + (size_t)(tt & 3) * BSZ;
    const char* Ard = buf + wm * 8192 + lanemix;
    const char* Brd = buf + 16384 + wn * 4096 + lanemix;
    STAGE(tt + 3);
#pragma unroll
    for (int mf = 0; mf < 8; ++mf) af[mf] = *(const s16x8*)(Ard + mf * 1024);
#pragma unroll
    for (int nf = 0; nf < 4; ++nf) bfr[nf] = *(const s16x8*)(Brd + nf * 1024);
    __builtin_amdgcn_s_setprio(1);
#pragma unroll
    for (int mf = 0; mf < 8; ++mf)
#pragma unroll
      for (int nf = 0; nf < 4; ++nf)
        acc[mf][nf] = mfma16(bfr[nf], af[mf], acc[mf][nf]);
    __builtin_amdgcn_s_setprio(0);
    if (tt + 1 < NT) {
      if (tt + 3 < NT)      asm volatile("s_waitcnt vmcnt(8)" ::: "memory");
      else if (tt + 2 < NT) asm volatile("s_waitcnt vmcnt(4)" ::: "memory");
      else                  asm volatile("s_waitcnt vmcnt(0)" ::: "memory");
      SBAR();
    }
  }
#undef STAGE

#pragma unroll
  for (int mf = 0; mf < 8; ++mf) {
    int row = m0 + wm * 128 + mf * 16 + (l & 15);
    u16* crow = C + (size_t)row * N + n0 + wn * 64 + (l >> 4) * 4;
#pragma unroll
    for (int nf = 0; nf < 4; ++nf) store4(crow + nf * 16, acc[mf][nf]);
  }
}

// ================= 256x128 4-phase bf16 GEMM (gemm2, round-5/8 verified best) =================
__global__ __launch_bounds__(512, 2) void gemm8pn_kernel(
    const u16* __restrict__ A, const u16* __restrict__ Bt, float* __restrict__ C,
    int M, int N, int K) {
  __shared__ __align__(16) char lds[98304];
  int nwg = gridDim.x;
  int bid = blockIdx.x;
  int cpx = nwg >> 3;
  int swz = (bid & 7) * cpx + (bid >> 3);
  int ntn = N >> 7;
  int bm = swz / ntn, bn = swz - bm * ntn;
  int m0 = bm << 8, n0 = bn << 7;
  int t = threadIdx.x, w = t >> 6, l = t & 63;
  int wm = w >> 2, wn = w & 3;
  int NT = K >> 6;

  unsigned offA[4], offB[2];
  int cA[4], cB[2];
#pragma unroll
  for (int u = 0; u < 4; ++u) {
    int c = u * 8 + w;
    cA[u] = c;
    int d = c * 1024 + l * 16;
    int s = d ^ ((((d >> 7) & 7)) << 4);
    offA[u] = (unsigned)(m0 + (s >> 7)) * (unsigned)(K * 2) + (unsigned)(s & 127);
  }
#pragma unroll
  for (int u = 0; u < 2; ++u) {
    int c = u * 8 + w;
    cB[u] = c;
    int d = c * 1024 + l * 16;
    int s = d ^ ((((d >> 7) & 7)) << 4);
    offB[u] = (unsigned)(n0 + (s >> 7)) * (unsigned)(K * 2) + (unsigned)(s & 127);
  }
  const char* Ab = (const char*)A;
  const char* Bb = (const char*)Bt;

#define STG_A(tile, u) do { int _t = (tile); if (_t < NT) {                    \
    gload16(Ab + (size_t)(offA[u] + (unsigned)_t * 128u),                       \
            lds + (_t & 1) * 49152 + cA[u] * 1024); } } while (0)
#define STG_B(tile, u) do { int _t = (tile); if (_t < NT) {                    \
    gload16(Bb + (size_t)(offB[u] + (unsigned)_t * 128u),                       \
            lds + (_t & 1) * 49152 + 32768 + cB[u] * 1024); } } while (0)

  int lanemix = ((l & 15) << 7) + ((((l >> 4) << 4) ^ ((l & 7) << 4)));
  int lanemix1 = lanemix ^ 64;

  f32x4 acc[8][2] = {};
  s16x8 af[4][2], bf0[2], bf1[2];

  STG_A(0, 0); STG_A(0, 1); STG_A(0, 2); STG_A(0, 3); STG_B(0, 0); STG_B(0, 1);
  STG_A(1, 0); STG_A(1, 1); STG_A(1, 2); STG_A(1, 3); STG_B(1, 0); STG_B(1, 1);
  asm volatile("s_waitcnt vmcnt(6)" ::: "memory");
  SBAR();

  for (int tt = 0; tt < NT; ++tt) {
    const char* ldsA = lds + (tt & 1) * 49152;
    const char* ldsB = ldsA + 32768;
    const char* Ard0 = ldsA + (wm << 14) + lanemix;
    const char* Ard1 = ldsA + (wm << 14) + lanemix1;
    const char* Brd0 = ldsB + (wn << 12) + lanemix;
    const char* Brd1 = ldsB + (wn << 12) + lanemix1;

    // ---- phase 1: mf0-3 x nf0 ----
#pragma unroll
    for (int mf = 0; mf < 4; ++mf) {
      af[mf][0] = *(const s16x8*)(Ard0 + mf * 2048);
      af[mf][1] = *(const s16x8*)(Ard1 + mf * 2048);
    }
    bf0[0] = *(const s16x8*)(Brd0);
    bf0[1] = *(const s16x8*)(Brd1);
    SBAR();
    __builtin_amdgcn_s_setprio(1);
#pragma unroll
    for (int mf = 0; mf < 4; ++mf) {
      acc[mf][0] = mfma16(bf0[0], af[mf][0], acc[mf][0]);
      acc[mf][0] = mfma16(bf0[1], af[mf][1], acc[mf][0]);
    }
    __builtin_amdgcn_s_setprio(0);
    SBAR();

    // ---- phase 2: mf0-3 x nf1 ; stage A units 0,2 ----
    bf1[0] = *(const s16x8*)(Brd0 + 2048);
    bf1[1] = *(const s16x8*)(Brd1 + 2048);
    STG_A(tt + 2, 0); STG_A(tt + 2, 2);
    SBAR();
    __builtin_amdgcn_s_setprio(1);
#pragma unroll
    for (int mf = 0; mf < 4; ++mf) {
      acc[mf][1] = mfma16(bf1[0], af[mf][0], acc[mf][1]);
      acc[mf][1] = mfma16(bf1[1], af[mf][1], acc[mf][1]);
    }
    __builtin_amdgcn_s_setprio(0);
    SBAR();

    // ---- phase 3: mf4-7 x nf0 ; stage B units ----
#pragma unroll
    for (int mf = 0; mf < 4; ++mf) {
      af[mf][0] = *(const s16x8*)(Ard0 + (mf + 4) * 2048);
      af[mf][1] = *(const s16x8*)(Ard1 + (mf + 4) * 2048);
    }
    STG_B(tt + 2, 0); STG_B(tt + 2, 1);
    SBAR();
    __builtin_amdgcn_s_setprio(1);
#pragma unroll
    for (int mf = 0; mf < 4; ++mf) {
      acc[mf + 4][0] = mfma16(bf0[0], af[mf][0], acc[mf + 4][0]);
      acc[mf + 4][0] = mfma16(bf0[1], af[mf][1], acc[mf + 4][0]);
    }
    __builtin_amdgcn_s_setprio(0);
    SBAR();

    // ---- phase 4: mf4-7 x nf1 ; stage A units 1,3 ----
    STG_A(tt + 2, 1); STG_A(tt + 2, 3);
    SBAR();
    __builtin_amdgcn_s_setprio(1);
#pragma unroll
    for (int mf = 0; mf < 4; ++mf) {
      acc[mf + 4][1] = mfma16(bf1[0], af[mf][0], acc[mf + 4][1]);
      acc[mf + 4][1] = mfma16(bf1[1], af[mf][1], acc[mf + 4][1]);
    }
    __builtin_amdgcn_s_setprio(0);
    if (tt < NT - 2) asm volatile("s_waitcnt vmcnt(6)" ::: "memory");
    else             asm volatile("s_waitcnt vmcnt(0)" ::: "memory");
    SBAR();
  }
#undef STG_A
#undef STG_B

#pragma unroll
  for (int mf = 0; mf < 8; ++mf) {
    int row = m0 + wm * 128 + mf * 16 + (l & 15);
    float* crow = C + (size_t)row * N + n0 + wn * 32 + (l >> 4) * 4;
#pragma unroll
    for (int nf = 0; nf < 2; ++nf) store4(crow + nf * 16, acc[mf][nf]);
  }
}

// ========== RoPE+conv(k)  |  conv(v)+transpose  (Q handled inside attn) ==========
__global__ void rcvt_kernel(const u16* __restrict__ qkv, const float* __restrict__ cosT,
                            const float* __restrict__ sinT, const float* __restrict__ convk,
                            const float* __restrict__ convv,
                            u16* __restrict__ kb, u16* __restrict__ vt) {
  int t = threadIdx.x;
  if (blockIdx.x < 4096) {
    int row = blockIdx.x;
    int b = row >> 11, s = row & 2047;
    const u16* kr = qkv + (size_t)row * 4096 + 2048;
#pragma unroll
    for (int i = 0; i < 2; ++i) {
      int p = i * 256 + t;
      int h = p >> 6, d = p & 63;
      float c = cosT[s * 64 + d], sn = sinT[s * 64 + d];
      float x1 = bf2f(kr[h * 128 + d]), x2 = bf2f(kr[h * 128 + 64 + d]);
      float r1 = x1 * c - x2 * sn, r2 = x2 * c + x1 * sn;
      float p1 = 0.f, p2 = 0.f;
      if (s > 0) {
        const u16* kp = kr - 4096;
        float cp = cosT[(s - 1) * 64 + d], sp = sinT[(s - 1) * 64 + d];
        float y1 = bf2f(kp[h * 128 + d]), y2 = bf2f(kp[h * 128 + 64 + d]);
        p1 = y1 * cp - y2 * sp;
        p2 = y2 * cp + y1 * sp;
      }
      float w0 = convk[h * 2], w1 = convk[h * 2 + 1];
      size_t o = (((size_t)b * 8 + h) * 2048 + s) * 128;
      kb[o + d] = f2bf(w0 * p1 + w1 * r1);
      kb[o + 64 + d] = f2bf(w0 * p2 + w1 * r2);
    }
  } else {
    __shared__ u16 lt[128][72];
    int idx = blockIdx.x - 4096;
    int st = idx & 31, bh = idx >> 5;
    int b = bh >> 3, h = bh & 7;
    int s0 = st * 64;
    float w0 = convv[h * 2], w1 = convv[h * 2 + 1];
#pragma unroll
    for (int i = 0; i < 32; ++i) {
      int flat = i * 256 + t;
      int sl = flat >> 7, d = flat & 127;
      int s = s0 + sl;
      int row = b * 2048 + s;
      float x = bf2f(qkv[(size_t)row * 4096 + 3072 + h * 128 + d]);
      float xp = (s > 0) ? bf2f(qkv[(size_t)(row - 1) * 4096 + 3072 + h * 128 + d]) : 0.f;
      lt[d][sl] = f2bf(w0 * xp + w1 * x);
    }
    __syncthreads();
#pragma unroll
    for (int i = 0; i < 32; ++i) {
      int flat = i * 256 + t;
      int d = flat >> 6, sl = flat & 63;
      vt[((size_t)(b * 8 + h) * 128 + d) * 2048 + s0 + sl] = lt[d][sl];
    }
  }
}

// ============ sliding-window GQA flash attention, swapped-QK^T 32x32 ============
// Q read raw from qkv; RoPE in-register; scores in log2-domain (qs *= log2(e))
// so P = v_exp_f32(S) directly — no per-score mul by 1.4427.
__global__ __launch_bounds__(256, 2) void attn2_kernel(
    const u16* __restrict__ qkv, const float* __restrict__ cosT,
    const float* __restrict__ sinT, const u16* __restrict__ kbuf,
    const u16* __restrict__ vt, u16* __restrict__ ao) {
  __shared__ __align__(16) char lds[65536];  // [2] x { K 16KB | V 16KB }
  int qt = blockIdx.x, bh = blockIdx.y;
  int b = bh >> 4, h = bh & 15, kh = h >> 1;
  int t = threadIdx.x, w = t >> 6, l = t & 63;
  int i0 = qt * 128;
  int qbase = i0 + w * 32;
  int lq = l & 31, hi = l >> 5;
  int xorc = (l & 7) << 4;
  const char* Kg = (const char*)(kbuf + (size_t)(b * 8 + kh) * 2048 * 128);
  const char* Vg = (const char*)(vt + (size_t)(b * 8 + kh) * 128 * 2048);

  // ---- Q load from qkv + in-register RoPE; scale = log2(e)/sqrt(128) ----
  s16x8 qf[8];
  {
    const float qs = 0.12751747157186644f;  // 1.4426950408889634 / sqrt(128)
    int srow = qbase + lq;
    const u16* qp = qkv + ((size_t)(b * 2048 + srow)) * 4096 + h * 128 + 8 * hi;
    const float* cb = cosT + srow * 64 + 8 * hi;
    const float* sb = sinT + srow * 64 + 8 * hi;
#pragma unroll
    for (int kc = 0; kc < 4; ++kc) {
      s16x8 vlo = *(const s16x8*)(qp + kc * 16);
      s16x8 vhi = *(const s16x8*)(qp + 64 + kc * 16);
      float4 c0 = *(const float4*)(cb + kc * 16);
      float4 c1 = *(const float4*)(cb + kc * 16 + 4);
      float4 s0 = *(const float4*)(sb + kc * 16);
      float4 s1 = *(const float4*)(sb + kc * 16 + 4);
      float cc[8] = {c0.x, c0.y, c0.z, c0.w, c1.x, c1.y, c1.z, c1.w};
      float ss[8] = {s0.x, s0.y, s0.z, s0.w, s1.x, s1.y, s1.z, s1.w};
      u16 ol[8], oh[8];
#pragma unroll
      for (int j = 0; j < 8; ++j) {
        float xl = bf2f(((const u16*)&vlo)[j]);
        float xh = bf2f(((const u16*)&vhi)[j]);
        ol[j] = f2bf((xl * cc[j] - xh * ss[j]) * qs);
        oh[j] = f2bf((xh * cc[j] + xl * ss[j]) * qs);
      }
      qf[kc] = *(s16x8*)ol;
      qf[kc + 4] = *(s16x8*)oh;
    }
  }

  unsigned ksrc[4], vsrc[4], kdst[4], vdst[4];
#pragma unroll
  for (int i = 0; i < 4; ++i) {
    int c = w * 4 + i;
    int row = c * 4 + (l >> 4);
    int colb = (l & 15) * 16;
    ksrc[i] = (unsigned)(row * 256 + (colb ^ ((row & 7) << 4)));
    kdst[i] = (unsigned)(c * 1024);
    int d = c * 8 + (l >> 3);
    int cb2 = (l & 7) * 16;
    vsrc[i] = (unsigned)(d * 4096 + (cb2 ^ ((d & 7) << 4)));
    vdst[i] = (unsigned)(16384 + c * 1024);
  }

#define STAGEKV(tile, buf) do { int _j2 = (tile) << 6;                          \
    char* _lb = lds + ((buf) << 15);                                             \
    const char* _ks = Kg + (size_t)_j2 * 256;                                    \
    const char* _vs = Vg + (size_t)_j2 * 2;                                      \
    gload16(_ks + ksrc[0], _lb + kdst[0]); gload16(_vs + vsrc[0], _lb + vdst[0]);\
    gload16(_ks + ksrc[1], _lb + kdst[1]); gload16(_vs + vsrc[1], _lb + vdst[1]);\
    gload16(_ks + ksrc[2], _lb + kdst[2]); gload16(_vs + vsrc[2], _lb + vdst[2]);\
    gload16(_ks + ksrc[3], _lb + kdst[3]); gload16(_vs + vsrc[3], _lb + vdst[3]);\
  } while (0)

  int lo = i0 - 1023; if (lo < 0) lo = 0;
  int tk0 = lo >> 6, tk1 = (i0 + 127) >> 6;

  f32x16 acco[4] = {};
  float ls0 = 0.f, ls1 = 0.f, ls2 = 0.f, ls3 = 0.f;

  int cur = 0;
  STAGEKV(tk0, 0);
  asm volatile("s_waitcnt vmcnt(0)" ::: "memory");
  SBAR();

  for (int tk = tk0; tk <= tk1; ++tk) {
    int j0 = tk << 6;
    if (tk < tk1) STAGEKV(tk + 1, cur ^ 1);
    bool relevant = (j0 <= qbase + 31) && (j0 + 63 >= qbase - 1023);
    if (relevant) {
      const char* Kl = lds + (cur << 15);
      const char* Vl = Kl + 16384;
      const char* Krow = Kl + lq * 256;
      f32x16 ps0 = {}, ps1 = {};
      __builtin_amdgcn_s_setprio(1);
#pragma unroll
      for (int kc = 0; kc < 8; ++kc) {
        s16x8 kf = *(const s16x8*)(Krow + ((kc * 32 + hi * 16) ^ xorc));
        ps0 = mfma32(kf, qf[kc], ps0);
      }
#pragma unroll
      for (int kc = 0; kc < 8; ++kc) {
        s16x8 kf = *(const s16x8*)(Krow + 8192 + ((kc * 32 + hi * 16) ^ xorc));
        ps1 = mfma32(kf, qf[kc], ps1);
      }
      __builtin_amdgcn_s_setprio(0);
      bool domask = (j0 + 63 > qbase) || (qbase + 31 - j0 >= 1024);
      int di0 = qbase + lq - j0;
      float pe[32];
#pragma unroll
      for (int r = 0; r < 16; ++r) {
        float s0 = ps0[r], s1 = ps1[r];
        if (domask) {
          int crow = (r & 3) + 8 * (r >> 2) + 4 * hi;
          if ((unsigned)(di0 - crow) >= 1024u) s0 = -1e30f;
          if ((unsigned)(di0 - 32 - crow) >= 1024u) s1 = -1e30f;
        }
        float e0 = exp2fast(s0), e1 = exp2fast(s1);
        pe[r] = e0; pe[16 + r] = e1;
        if ((r & 3) == 0) { ls0 += e0 + e1; }
        else if ((r & 3) == 1) { ls1 += e0 + e1; }
        else if ((r & 3) == 2) { ls2 += e0 + e1; }
        else { ls3 += e0 + e1; }
      }
      unsigned pk[16];
#pragma unroll
      for (int p = 0; p < 16; ++p) {
        asm("v_cvt_pk_bf16_f32 %0, %1, %2" : "=v"(pk[p]) : "v"(pe[2 * p]), "v"(pe[2 * p + 1]));
      }
      s16x8 pa[4];
#pragma unroll
      for (int ks = 0; ks < 4; ++ks) {
        int base = (ks >> 1) * 8 + (ks & 1) * 4;
        unsigned keep0 = hi ? pk[base + 2] : pk[base + 0];
        unsigned keep1 = hi ? pk[base + 3] : pk[base + 1];
        unsigned send0 = hi ? pk[base + 0] : pk[base + 2];
        unsigned send1 = hi ? pk[base + 1] : pk[base + 3];
        unsigned recv0 = (unsigned)__shfl_xor((int)send0, 32);
        unsigned recv1 = (unsigned)__shfl_xor((int)send1, 32);
        union { unsigned u[4]; s16x8 v; } pu;
        pu.u[0] = hi ? recv0 : keep0;
        pu.u[1] = hi ? recv1 : keep1;
        pu.u[2] = hi ? keep0 : recv0;
        pu.u[3] = hi ? keep1 : recv1;
        pa[ks] = pu.v;
      }
      __builtin_amdgcn_s_setprio(1);
#pragma unroll
      for (int db = 0; db < 4; ++db) {
        const char* Vrow = Vl + db * 4096 + lq * 128;
#pragma unroll
        for (int ks = 0; ks < 4; ++ks) {
          s16x8 vf = *(const s16x8*)(Vrow + ((ks * 32 + hi * 16) ^ xorc));
          acco[db] = mfma32(pa[ks], vf, acco[db]);
        }
      }
      __builtin_amdgcn_s_setprio(0);
    }
    asm volatile("s_waitcnt vmcnt(0)" ::: "memory");
    SBAR();
    cur ^= 1;
  }
#undef STAGEKV

  float lrow = (ls0 + ls1) + (ls2 + ls3);
  float lt2 = lrow + __shfl_xor(lrow, 32);
  float rinv = 1.f / lt2;
#pragma unroll
  for (int r = 0; r < 16; ++r) {
    int qidx = (r & 3) + 8 * (r >> 2) + 4 * hi;
    float rv = __shfl(rinv, qidx);
    int i = qbase + qidx;
    u16* orow = ao + ((size_t)(b * 2048 + i)) * 2048 + h * 128 + lq;
#pragma unroll
    for (int db = 0; db < 4; ++db)
      orow[db * 32] = f2bf(acco[db][r] * rv);
  }
}

extern "C" void kernel_launch(void* const* d_in, const int* in_sizes, int n_in,
                              void* d_out, int out_size, void* d_ws, size_t ws_size,
                              hipStream_t stream) {
  (void)in_sizes; (void)n_in; (void)out_size; (void)ws_size;
  const float* hidden = (const float*)d_in[0];
  const float* W_pack = (const float*)d_in[1];
  const float* W_o    = (const float*)d_in[2];
  const float* conv_k = (const float*)d_in[3];
  const float* conv_v = (const float*)d_in[4];

  char* ws = (char*)d_ws;
  const size_t MB = 1u << 20;
  u16* hA    = (u16*)(ws + 0);          // 16 MB  hidden bf16 [4096][2048]
  u16* wpT   = (u16*)(ws + 16 * MB);    // 16 MB  W_pack^T bf16 [4096][2048]
  u16* woT   = (u16*)(ws + 32 * MB);    //  8 MB  W_o^T bf16 [2048][2048]
  u16* qkv   = (u16*)(ws + 40 * MB);    // 32 MB  qkv bf16 [4096][4096]
  u16* attnb = (u16*)(ws + 72 * MB);    // 16 MB  attention out bf16 [4096][2048]
  u16* kbuf  = (u16*)(ws + 88 * MB);    //  8 MB  k roped+conv [b,kh,s,128]
  u16* vtb   = (u16*)(ws + 96 * MB);    //  8 MB  v conv, transposed [b,kh,d,s]
  float* cosT = (float*)(ws + 104 * MB);
  float* sinT = (float*)(ws + 104 * MB + 524288);

  prep_kernel<<<7680, 256, 0, stream>>>(hidden, W_pack, W_o, hA, wpT, woT, cosT, sinT);
  gemm_ring_kernel<<<256, 512, 0, stream>>>(hA, wpT, qkv, 4096, 4096, 2048);
  rcvt_kernel<<<4608, 256, 0, stream>>>(qkv, cosT, sinT, conv_k, conv_v, kbuf, vtb);
  attn2_kernel<<<dim3(16, 32), 256, 0, stream>>>(qkv, cosT, sinT, kbuf, vtb, attnb);
  gemm8pn_kernel<<<256, 512, 0, stream>>>(attnb, woT, (float*)d_out, 4096, 2048, 2048);
}

// Round 12
// 190.739 us; speedup vs baseline: 1.0269x; 1.0269x over previous
//
#include <hip/hip_runtime.h>

#define DI __device__ __forceinline__

typedef unsigned short u16;
typedef __attribute__((ext_vector_type(8))) short s16x8;
typedef __attribute__((ext_vector_type(8))) unsigned short u16x8;
typedef __attribute__((ext_vector_type(4))) float f32x4;
typedef __attribute__((ext_vector_type(16))) float f32x16;

DI u16 f2bf(float x) {
  union { float f; unsigned u; } a; a.f = x;
  unsigned r = a.u + 0x7FFFu + ((a.u >> 16) & 1u);
  return (u16)(r >> 16);
}
DI float bf2f(u16 u) {
  union { unsigned u; float f; } a; a.u = ((unsigned)u) << 16;
  return a.f;
}
DI void gload16(const void* g, void* l) {
  __builtin_amdgcn_global_load_lds(
      (const __attribute__((address_space(1))) unsigned int*)g,
      (__attribute__((address_space(3))) unsigned int*)l, 16, 0, 0);
}
DI f32x4 mfma16(s16x8 a, s16x8 b, f32x4 c) {
  return __builtin_amdgcn_mfma_f32_16x16x32_bf16(a, b, c, 0, 0, 0);
}
DI f32x16 mfma32(s16x8 a, s16x8 b, f32x16 c) {
  return __builtin_amdgcn_mfma_f32_32x32x16_bf16(a, b, c, 0, 0, 0);
}

DI void store4(u16* p, f32x4 v) {
  union { u16 u[4]; unsigned long long ll; } o;
  o.u[0] = f2bf(v[0]); o.u[1] = f2bf(v[1]); o.u[2] = f2bf(v[2]); o.u[3] = f2bf(v[3]);
  *(unsigned long long*)p = o.ll;  // 8B
}
DI void store4(float* p, f32x4 v) { *(f32x4*)p = v; }  // 16B

#define SBAR() asm volatile("s_barrier" ::: "memory")

// ================= fused prep: cvt(hidden) + W_pack^T + W_o^T + rope table =================
__global__ __launch_bounds__(256) void prep_kernel(
    const float* __restrict__ hidden, const float* __restrict__ W_pack,
    const float* __restrict__ W_o, u16* __restrict__ hA, u16* __restrict__ wpT,
    u16* __restrict__ woT, float* __restrict__ cosT, float* __restrict__ sinT) {
  int bi = blockIdx.x;
  int t = threadIdx.x;
  if (bi < 4096) {
    int i = bi * 256 + t;
    const float4* p = (const float4*)hidden + (size_t)i * 2;
    float4 a = p[0], b = p[1];
    u16x8 o;
    o[0] = f2bf(a.x); o[1] = f2bf(a.y); o[2] = f2bf(a.z); o[3] = f2bf(a.w);
    o[4] = f2bf(b.x); o[5] = f2bf(b.y); o[6] = f2bf(b.z); o[7] = f2bf(b.w);
    *((u16x8*)hA + i) = o;
  } else if (bi < 7168) {
    const float* W; u16* Wt; int R, C, c0, r0;
    if (bi < 6144) {
      int idx = bi - 4096;
      W = W_pack; Wt = wpT; R = 2048; C = 4096;
      c0 = (idx & 63) * 64; r0 = (idx >> 6) * 64;
    } else {
      int idx = bi - 6144;
      W = W_o; Wt = woT; R = 2048; C = 2048;
      c0 = (idx & 31) * 64; r0 = (idx >> 5) * 64;
    }
    __shared__ u16 tile[64][65];
#pragma unroll
    for (int i = 0; i < 16; ++i) {
      int flat = i * 256 + t;
      int r = flat >> 6, c = flat & 63;
      tile[r][c] = f2bf(W[(size_t)(r0 + r) * C + (c0 + c)]);
    }
    __syncthreads();
#pragma unroll
    for (int i = 0; i < 16; ++i) {
      int flat = i * 256 + t;
      int c = flat >> 6, r = flat & 63;
      Wt[(size_t)(c0 + c) * R + (r0 + r)] = tile[r][c];
    }
  } else {
    int i = (bi - 7168) * 256 + t;
    int s = i >> 6, d = i & 63;
    float inv = expf(-(float)d * (11.5129254649702295f / 64.f));
    float f = (float)s * inv;
    cosT[i] = cosf(f);
    sinT[i] = sinf(f);
  }
}

// ================= 256x256 ring-buffer bf16 GEMM (gemm1) =================
__global__ __launch_bounds__(512, 2) void gemm_ring_kernel(
    const u16* __restrict__ A, const u16* __restrict__ Bt, u16* __restrict__ C,
    int M, int N, int K) {
  constexpr int BSZ = 32768;  // A 16KB + B 16KB
  __shared__ __align__(16) char lds[4 * BSZ];
  int nwg = gridDim.x, bid = blockIdx.x;
  int cpx = nwg >> 3;
  int swz = (bid & 7) * cpx + (bid >> 3);  // bijective: nwg % 8 == 0
  int ntn = N >> 8;
  int bm = swz / ntn, bn = swz - bm * ntn;
  int m0 = bm << 8, n0 = bn << 8;
  int t = threadIdx.x, w = t >> 6, l = t & 63;
  int wm = w >> 2, wn = w & 3;
  int NT = K >> 5;  // K-tiles of 32

  unsigned srcA[2], srcB[2];
  unsigned scol = (unsigned)(((t & 3) ^ ((t >> 3) & 3)) << 4);
#pragma unroll
  for (int u = 0; u < 2; ++u) {
    srcA[u] = (unsigned)(m0 + u * 128 + (t >> 2)) * (unsigned)(K * 2) + scol;
    srcB[u] = (unsigned)(n0 + u * 128 + (t >> 2)) * (unsigned)(K * 2) + scol;
  }
  unsigned dstT = (unsigned)(t * 16);
  const char* Ab = (const char*)A;
  const char* Bb = (const char*)Bt;

#define STAGE(tile) do { int _t = (tile); if (_t < NT) {                        \
    char* _bb = lds + (size_t)(_t & 3) * BSZ;                                    \
    unsigned _k = (unsigned)_t * 64u;                                            \
    gload16(Ab + (size_t)(srcA[0] + _k), _bb + dstT);                            \
    gload16(Ab + (size_t)(srcA[1] + _k), _bb + 8192 + dstT);                     \
    gload16(Bb + (size_t)(srcB[0] + _k), _bb + 16384 + dstT);                    \
    gload16(Bb + (size_t)(srcB[1] + _k), _bb + 24576 + dstT);                    \
  } } while (0)

  int lanemix = ((l & 15) << 6) + ((((l >> 4) ^ ((l >> 1) & 3))) << 4);

  f32x4 acc[8][4] = {};
  s16x8 af[8], bfr[4];

  STAGE(0); STAGE(1); STAGE(2);
  asm volatile("s_waitcnt vmcnt(8)" ::: "memory");
  SBAR();

  for (int tt = 0; tt < NT; ++tt) {
    char* buf = lds + (size_t)(tt & 3) * BSZ;
    const char* Ard = buf + wm * 8192 + lanemix;
    const char* Brd = buf + 16384 + wn * 4096 + lanemix;
    STAGE(tt + 3);
#pragma unroll
    for (int mf = 0; mf < 8; ++mf) af[mf] = *(const s16x8*)(Ard + mf * 1024);
#pragma unroll
    for (int nf = 0; nf < 4; ++nf) bfr[nf] = *(const s16x8*)(Brd + nf * 1024);
    __builtin_amdgcn_s_setprio(1);
#pragma unroll
    for (int mf = 0; mf < 8; ++mf)
#pragma unroll
      for (int nf = 0; nf < 4; ++nf)
        acc[mf][nf] = mfma16(bfr[nf], af[mf], acc[mf][nf]);
    __builtin_amdgcn_s_setprio(0);
    if (tt + 1 < NT) {
      if (tt + 3 < NT)      asm volatile("s_waitcnt vmcnt(8)" ::: "memory");
      else if (tt + 2 < NT) asm volatile("s_waitcnt vmcnt(4)" ::: "memory");
      else                  asm volatile("s_waitcnt vmcnt(0)" ::: "memory");
      SBAR();
    }
  }
#undef STAGE

#pragma unroll
  for (int mf = 0; mf < 8; ++mf) {
    int row = m0 + wm * 128 + mf * 16 + (l & 15);
    u16* crow = C + (size_t)row * N + n0 + wn * 64 + (l >> 4) * 4;
#pragma unroll
    for (int nf = 0; nf < 4; ++nf) store4(crow + nf * 16, acc[mf][nf]);
  }
}

// ================= 256x128 4-phase bf16 GEMM (gemm2, round-5 verified) =================
__global__ __launch_bounds__(512, 2) void gemm8pn_kernel(
    const u16* __restrict__ A, const u16* __restrict__ Bt, float* __restrict__ C,
    int M, int N, int K) {
  __shared__ __align__(16) char lds[98304];
  int nwg = gridDim.x;
  int bid = blockIdx.x;
  int cpx = nwg >> 3;
  int swz = (bid & 7) * cpx + (bid >> 3);
  int ntn = N >> 7;
  int bm = swz / ntn, bn = swz - bm * ntn;
  int m0 = bm << 8, n0 = bn << 7;
  int t = threadIdx.x, w = t >> 6, l = t & 63;
  int wm = w >> 2, wn = w & 3;
  int NT = K >> 6;

  unsigned offA[4], offB[2];
  int cA[4], cB[2];
#pragma unroll
  for (int u = 0; u < 4; ++u) {
    int c = u * 8 + w;
    cA[u] = c;
    int d = c * 1024 + l * 16;
    int s = d ^ ((((d >> 7) & 7)) << 4);
    offA[u] = (unsigned)(m0 + (s >> 7)) * (unsigned)(K * 2) + (unsigned)(s & 127);
  }
#pragma unroll
  for (int u = 0; u < 2; ++u) {
    int c = u * 8 + w;
    cB[u] = c;
    int d = c * 1024 + l * 16;
    int s = d ^ ((((d >> 7) & 7)) << 4);
    offB[u] = (unsigned)(n0 + (s >> 7)) * (unsigned)(K * 2) + (unsigned)(s & 127);
  }
  const char* Ab = (const char*)A;
  const char* Bb = (const char*)Bt;

#define STG_A(tile, u) do { int _t = (tile); if (_t < NT) {                    \
    gload16(Ab + (size_t)(offA[u] + (unsigned)_t * 128u),                       \
            lds + (_t & 1) * 49152 + cA[u] * 1024); } } while (0)
#define STG_B(tile, u) do { int _t = (tile); if (_t < NT) {                    \
    gload16(Bb + (size_t)(offB[u] + (unsigned)_t * 128u),                       \
            lds + (_t & 1) * 49152 + 32768 + cB[u] * 1024); } } while (0)

  int lanemix = ((l & 15) << 7) + ((((l >> 4) << 4) ^ ((l & 7) << 4)));
  int lanemix1 = lanemix ^ 64;

  f32x4 acc[8][2] = {};
  s16x8 af[4][2], bf0[2], bf1[2];

  STG_A(0, 0); STG_A(0, 1); STG_A(0, 2); STG_A(0, 3); STG_B(0, 0); STG_B(0, 1);
  STG_A(1, 0); STG_A(1, 1); STG_A(1, 2); STG_A(1, 3); STG_B(1, 0); STG_B(1, 1);
  asm volatile("s_waitcnt vmcnt(6)" ::: "memory");
  SBAR();

  for (int tt = 0; tt < NT; ++tt) {
    const char* ldsA = lds + (tt & 1) * 49152;
    const char* ldsB = ldsA + 32768;
    const char* Ard0 = ldsA + (wm << 14) + lanemix;
    const char* Ard1 = ldsA + (wm << 14) + lanemix1;
    const char* Brd0 = ldsB + (wn << 12) + lanemix;
    const char* Brd1 = ldsB + (wn << 12) + lanemix1;

    // ---- phase 1: mf0-3 x nf0 ----
#pragma unroll
    for (int mf = 0; mf < 4; ++mf) {
      af[mf][0] = *(const s16x8*)(Ard0 + mf * 2048);
      af[mf][1] = *(const s16x8*)(Ard1 + mf * 2048);
    }
    bf0[0] = *(const s16x8*)(Brd0);
    bf0[1] = *(const s16x8*)(Brd1);
    SBAR();
    __builtin_amdgcn_s_setprio(1);
#pragma unroll
    for (int mf = 0; mf < 4; ++mf) {
      acc[mf][0] = mfma16(bf0[0], af[mf][0], acc[mf][0]);
      acc[mf][0] = mfma16(bf0[1], af[mf][1], acc[mf][0]);
    }
    __builtin_amdgcn_s_setprio(0);
    SBAR();

    // ---- phase 2: mf0-3 x nf1 ; stage A units 0,2 ----
    bf1[0] = *(const s16x8*)(Brd0 + 2048);
    bf1[1] = *(const s16x8*)(Brd1 + 2048);
    STG_A(tt + 2, 0); STG_A(tt + 2, 2);
    SBAR();
    __builtin_amdgcn_s_setprio(1);
#pragma unroll
    for (int mf = 0; mf < 4; ++mf) {
      acc[mf][1] = mfma16(bf1[0], af[mf][0], acc[mf][1]);
      acc[mf][1] = mfma16(bf1[1], af[mf][1], acc[mf][1]);
    }
    __builtin_amdgcn_s_setprio(0);
    SBAR();

    // ---- phase 3: mf4-7 x nf0 ; stage B units ----
#pragma unroll
    for (int mf = 0; mf < 4; ++mf) {
      af[mf][0] = *(const s16x8*)(Ard0 + (mf + 4) * 2048);
      af[mf][1] = *(const s16x8*)(Ard1 + (mf + 4) * 2048);
    }
    STG_B(tt + 2, 0); STG_B(tt + 2, 1);
    SBAR();
    __builtin_amdgcn_s_setprio(1);
#pragma unroll
    for (int mf = 0; mf < 4; ++mf) {
      acc[mf + 4][0] = mfma16(bf0[0], af[mf][0], acc[mf + 4][0]);
      acc[mf + 4][0] = mfma16(bf0[1], af[mf][1], acc[mf + 4][0]);
    }
    __builtin_amdgcn_s_setprio(0);
    SBAR();

    // ---- phase 4: mf4-7 x nf1 ; stage A units 1,3 ----
    STG_A(tt + 2, 1); STG_A(tt + 2, 3);
    SBAR();
    __builtin_amdgcn_s_setprio(1);
#pragma unroll
    for (int mf = 0; mf < 4; ++mf) {
      acc[mf + 4][1] = mfma16(bf1[0], af[mf][0], acc[mf + 4][1]);
      acc[mf + 4][1] = mfma16(bf1[1], af[mf][1], acc[mf + 4][1]);
    }
    __builtin_amdgcn_s_setprio(0);
    if (tt < NT - 2) asm volatile("s_waitcnt vmcnt(6)" ::: "memory");
    else             asm volatile("s_waitcnt vmcnt(0)" ::: "memory");
    SBAR();
  }
#undef STG_A
#undef STG_B

#pragma unroll
  for (int mf = 0; mf < 8; ++mf) {
    int row = m0 + wm * 128 + mf * 16 + (l & 15);
    float* crow = C + (size_t)row * N + n0 + wn * 32 + (l >> 4) * 4;
#pragma unroll
    for (int nf = 0; nf < 2; ++nf) store4(crow + nf * 16, acc[mf][nf]);
  }
}

// ========== fused RoPE(q)+RoPE/conv(k)  |  conv(v)+transpose ==========
__global__ void rcvt_kernel(const u16* __restrict__ qkv, const float* __restrict__ cosT,
                            const float* __restrict__ sinT, const float* __restrict__ convk,
                            const float* __restrict__ convv,
                            u16* __restrict__ qb, u16* __restrict__ kb,
                            u16* __restrict__ vt) {
  int t = threadIdx.x;
  if (blockIdx.x < 4096) {
    const float qs = 0.08838834764831845f;  // 1/sqrt(128)
    int row = blockIdx.x;
    int b = row >> 11, s = row & 2047;
    const u16* qr = qkv + (size_t)row * 4096;
    u16* qo = qb + (size_t)row * 2048;
#pragma unroll
    for (int i = 0; i < 4; ++i) {
      int p = i * 256 + t;
      int h = p >> 6, d = p & 63;
      float x1 = bf2f(qr[h * 128 + d]), x2 = bf2f(qr[h * 128 + 64 + d]);
      float c = cosT[s * 64 + d], sn = sinT[s * 64 + d];
      qo[h * 128 + d] = f2bf((x1 * c - x2 * sn) * qs);
      qo[h * 128 + 64 + d] = f2bf((x2 * c + x1 * sn) * qs);
    }
    const u16* kr = qr + 2048;
#pragma unroll
    for (int i = 0; i < 2; ++i) {
      int p = i * 256 + t;
      int h = p >> 6, d = p & 63;
      float c = cosT[s * 64 + d], sn = sinT[s * 64 + d];
      float x1 = bf2f(kr[h * 128 + d]), x2 = bf2f(kr[h * 128 + 64 + d]);
      float r1 = x1 * c - x2 * sn, r2 = x2 * c + x1 * sn;
      float p1 = 0.f, p2 = 0.f;
      if (s > 0) {
        const u16* kp = kr - 4096;
        float cp = cosT[(s - 1) * 64 + d], sp = sinT[(s - 1) * 64 + d];
        float y1 = bf2f(kp[h * 128 + d]), y2 = bf2f(kp[h * 128 + 64 + d]);
        p1 = y1 * cp - y2 * sp;
        p2 = y2 * cp + y1 * sp;
      }
      float w0 = convk[h * 2], w1 = convk[h * 2 + 1];
      size_t o = (((size_t)b * 8 + h) * 2048 + s) * 128;
      kb[o + d] = f2bf(w0 * p1 + w1 * r1);
      kb[o + 64 + d] = f2bf(w0 * p2 + w1 * r2);
    }
  } else {
    __shared__ u16 lt[128][72];
    int idx = blockIdx.x - 4096;
    int st = idx & 31, bh = idx >> 5;
    int b = bh >> 3, h = bh & 7;
    int s0 = st * 64;
    float w0 = convv[h * 2], w1 = convv[h * 2 + 1];
#pragma unroll
    for (int i = 0; i < 32; ++i) {
      int flat = i * 256 + t;
      int sl = flat >> 7, d = flat & 127;
      int s = s0 + sl;
      int row = b * 2048 + s;
      float x = bf2f(qkv[(size_t)row * 4096 + 3072 + h * 128 + d]);
      float xp = (s > 0) ? bf2f(qkv[(size_t)(row - 1) * 4096 + 3072 + h * 128 + d]) : 0.f;
      lt[d][sl] = f2bf(w0 * xp + w1 * x);
    }
    __syncthreads();
#pragma unroll
    for (int i = 0; i < 32; ++i) {
      int flat = i * 256 + t;
      int d = flat >> 6, sl = flat & 63;
      vt[((size_t)(b * 8 + h) * 128 + d) * 2048 + s0 + sl] = lt[d][sl];
    }
  }
}

// ============ sliding-window GQA flash attention, swapped-QK^T 32x32 ============
__global__ __launch_bounds__(256, 2) void attn2_kernel(
    const u16* __restrict__ qb, const u16* __restrict__ kbuf, const u16* __restrict__ vt,
    u16* __restrict__ ao) {
  __shared__ __align__(16) char lds[65536];  // [2] x { K 16KB | V 16KB }
  int qt = blockIdx.x, bh = blockIdx.y;
  int b = bh >> 4, h = bh & 15, kh = h >> 1;
  int t = threadIdx.x, w = t >> 6, l = t & 63;
  int i0 = qt * 128;
  int qbase = i0 + w * 32;
  int lq = l & 31, hi = l >> 5;
  int xorc = (l & 7) << 4;
  const char* Kg = (const char*)(kbuf + (size_t)(b * 8 + kh) * 2048 * 128);
  const char* Vg = (const char*)(vt + (size_t)(b * 8 + kh) * 128 * 2048);

  s16x8 qf[8];
  {
    const u16* qp = qb + ((size_t)(b * 2048 + qbase + lq)) * 2048 + h * 128 + 8 * hi;
#pragma unroll
    for (int kc = 0; kc < 8; ++kc) qf[kc] = *(const s16x8*)(qp + kc * 16);
  }

  unsigned ksrc[4], vsrc[4], kdst[4], vdst[4];
#pragma unroll
  for (int i = 0; i < 4; ++i) {
    int c = w * 4 + i;
    int row = c * 4 + (l >> 4);
    int colb = (l & 15) * 16;
    ksrc[i] = (unsigned)(row * 256 + (colb ^ ((row & 7) << 4)));
    kdst[i] = (unsigned)(c * 1024);
    int d = c * 8 + (l >> 3);
    int cb2 = (l & 7) * 16;
    vsrc[i] = (unsigned)(d * 4096 + (cb2 ^ ((d & 7) << 4)));
    vdst[i] = (unsigned)(16384 + c * 1024);
  }

#define STAGEKV(tile, buf) do { int _j2 = (tile) << 6;                          \
    char* _lb = lds + ((buf) << 15);                                             \
    const char* _ks = Kg + (size_t)_j2 * 256;                                    \
    const char* _vs = Vg + (size_t)_j2 * 2;                                      \
    gload16(_ks + ksrc[0], _lb + kdst[0]); gload16(_vs + vsrc[0], _lb + vdst[0]);\
    gload16(_ks + ksrc[1], _lb + kdst[1]); gload16(_vs + vsrc[1], _lb + vdst[1]);\
    gload16(_ks + ksrc[2], _lb + kdst[2]); gload16(_vs + vsrc[2], _lb + vdst[2]);\
    gload16(_ks + ksrc[3], _lb + kdst[3]); gload16(_vs + vsrc[3], _lb + vdst[3]);\
  } while (0)

  int lo = i0 - 1023; if (lo < 0) lo = 0;
  int tk0 = lo >> 6, tk1 = (i0 + 127) >> 6;

  f32x16 acco[4] = {};
  float ls0 = 0.f, ls1 = 0.f, ls2 = 0.f, ls3 = 0.f;

  int cur = 0;
  STAGEKV(tk0, 0);
  asm volatile("s_waitcnt vmcnt(0)" ::: "memory");
  SBAR();

  for (int tk = tk0; tk <= tk1; ++tk) {
    int j0 = tk << 6;
    if (tk < tk1) STAGEKV(tk + 1, cur ^ 1);
    bool relevant = (j0 <= qbase + 31) && (j0 + 63 >= qbase - 1023);
    if (relevant) {
      const char* Kl = lds + (cur << 15);
      const char* Vl = Kl + 16384;
      const char* Krow = Kl + lq * 256;
      f32x16 ps0 = {}, ps1 = {};
      __builtin_amdgcn_s_setprio(1);
#pragma unroll
      for (int kc = 0; kc < 8; ++kc) {
        s16x8 kf = *(const s16x8*)(Krow + ((kc * 32 + hi * 16) ^ xorc));
        ps0 = mfma32(kf, qf[kc], ps0);
      }
#pragma unroll
      for (int kc = 0; kc < 8; ++kc) {
        s16x8 kf = *(const s16x8*)(Krow + 8192 + ((kc * 32 + hi * 16) ^ xorc));
        ps1 = mfma32(kf, qf[kc], ps1);
      }
      __builtin_amdgcn_s_setprio(0);
      bool domask = (j0 + 63 > qbase) || (qbase + 31 - j0 >= 1024);
      int di0 = qbase + lq - j0;
      float pe[32];
#pragma unroll
      for (int r = 0; r < 16; ++r) {
        float s0 = ps0[r], s1 = ps1[r];
        if (domask) {
          int crow = (r & 3) + 8 * (r >> 2) + 4 * hi;
          if ((unsigned)(di0 - crow) >= 1024u) s0 = -1e30f;
          if ((unsigned)(di0 - 32 - crow) >= 1024u) s1 = -1e30f;
        }
        float e0 = __expf(s0), e1 = __expf(s1);
        pe[r] = e0; pe[16 + r] = e1;
        if ((r & 3) == 0) { ls0 += e0 + e1; }
        else if ((r & 3) == 1) { ls1 += e0 + e1; }
        else if ((r & 3) == 2) { ls2 += e0 + e1; }
        else { ls3 += e0 + e1; }
      }
      unsigned pk[16];
#pragma unroll
      for (int p = 0; p < 16; ++p) {
        asm("v_cvt_pk_bf16_f32 %0, %1, %2" : "=v"(pk[p]) : "v"(pe[2 * p]), "v"(pe[2 * p + 1]));
      }
      s16x8 pa[4];
#pragma unroll
      for (int ks = 0; ks < 4; ++ks) {
        int base = (ks >> 1) * 8 + (ks & 1) * 4;
        unsigned keep0 = hi ? pk[base + 2] : pk[base + 0];
        unsigned keep1 = hi ? pk[base + 3] : pk[base + 1];
        unsigned send0 = hi ? pk[base + 0] : pk[base + 2];
        unsigned send1 = hi ? pk[base + 1] : pk[base + 3];
        unsigned recv0 = (unsigned)__shfl_xor((int)send0, 32);
        unsigned recv1 = (unsigned)__shfl_xor((int)send1, 32);
        union { unsigned u[4]; s16x8 v; } pu;
        pu.u[0] = hi ? recv0 : keep0;
        pu.u[1] = hi ? recv1 : keep1;
        pu.u[2] = hi ? keep0 : recv0;
        pu.u[3] = hi ? keep1 : recv1;
        pa[ks] = pu.v;
      }
      __builtin_amdgcn_s_setprio(1);
#pragma unroll
      for (int db = 0; db < 4; ++db) {
        const char* Vrow = Vl + db * 4096 + lq * 128;
#pragma unroll
        for (int ks = 0; ks < 4; ++ks) {
          s16x8 vf = *(const s16x8*)(Vrow + ((ks * 32 + hi * 16) ^ xorc));
          acco[db] = mfma32(pa[ks], vf, acco[db]);
        }
      }
      __builtin_amdgcn_s_setprio(0);
    }
    asm volatile("s_waitcnt vmcnt(0)" ::: "memory");
    SBAR();
    cur ^= 1;
  }
#undef STAGEKV

  float lrow = (ls0 + ls1) + (ls2 + ls3);
  float lt2 = lrow + __shfl_xor(lrow, 32);
  float rinv = 1.f / lt2;
#pragma unroll
  for (int r = 0; r < 16; ++r) {
    int qidx = (r & 3) + 8 * (r >> 2) + 4 * hi;
    float rv = __shfl(rinv, qidx);
    int i = qbase + qidx;
    u16* orow = ao + ((size_t)(b * 2048 + i)) * 2048 + h * 128 + lq;
#pragma unroll
    for (int db = 0; db < 4; ++db)
      orow[db * 32] = f2bf(acco[db][r] * rv);
  }
}

extern "C" void kernel_launch(void* const* d_in, const int* in_sizes, int n_in,
                              void* d_out, int out_size, void* d_ws, size_t ws_size,
                              hipStream_t stream) {
  (void)in_sizes; (void)n_in; (void)out_size; (void)ws_size;
  const float* hidden = (const float*)d_in[0];
  const float* W_pack = (const float*)d_in[1];
  const float* W_o    = (const float*)d_in[2];
  const float* conv_k = (const float*)d_in[3];
  const float* conv_v = (const float*)d_in[4];

  char* ws = (char*)d_ws;
  const size_t MB = 1u << 20;
  u16* hA    = (u16*)(ws + 0);          // 16 MB  hidden bf16 [4096][2048]
  u16* wpT   = (u16*)(ws + 16 * MB);    // 16 MB  W_pack^T bf16 [4096][2048]
  u16* woT   = (u16*)(ws + 32 * MB);    //  8 MB  W_o^T bf16 [2048][2048]
  u16* qkv   = (u16*)(ws + 40 * MB);    // 32 MB  qkv bf16 [4096][4096]
  u16* qb    = (u16*)(ws + 72 * MB);    // 16 MB  q roped+scaled [b,s,h,128]
  u16* kbuf  = (u16*)(ws + 88 * MB);    //  8 MB  k roped+conv [b,kh,s,128]
  u16* vtb   = (u16*)(ws + 96 * MB);    //  8 MB  v conv, transposed [b,kh,d,s]
  float* cosT = (float*)(ws + 104 * MB);
  float* sinT = (float*)(ws + 104 * MB + 524288);
  u16* attnb = qkv;                     // alias: qkv dead after rcvt

  prep_kernel<<<7680, 256, 0, stream>>>(hidden, W_pack, W_o, hA, wpT, woT, cosT, sinT);
  gemm_ring_kernel<<<256, 512, 0, stream>>>(hA, wpT, qkv, 4096, 4096, 2048);
  rcvt_kernel<<<4608, 256, 0, stream>>>(qkv, cosT, sinT, conv_k, conv_v, qb, kbuf, vtb);
  attn2_kernel<<<dim3(16, 32), 256, 0, stream>>>(qb, kbuf, vtb, attnb);
  gemm8pn_kernel<<<256, 512, 0, stream>>>(attnb, woT, (float*)d_out, 4096, 2048, 2048);
}